// Round 12
// baseline (1118.607 us; speedup 1.0000x reference)
//
#include <hip/hip_runtime.h>
#include <stdint.h>

#define F_DIM 128
#define H_DIM 64
#define K_DIM 16
#define BUK_SH 7
#define BN 128          // nodes per bucket
#define NCH 256

typedef _Float16 half2v __attribute__((ext_vector_type(2)));
typedef _Float16 half4 __attribute__((ext_vector_type(4)));
typedef _Float16 f16x8 __attribute__((ext_vector_type(8)));
typedef float f32x4 __attribute__((ext_vector_type(4)));

// ---- radix-partition edge binning (4 kernels; no per-node CSR needed) --
__global__ __launch_bounds__(256) void k_hist(const int* __restrict__ dst,
                                              int* __restrict__ hist,
                                              int E, int CH, int NBUK) {
    __shared__ int h[1024];
    int t = threadIdx.x, c = blockIdx.x;
    for (int i = t; i < NBUK; i += 256) h[i] = 0;
    __syncthreads();
    int s = c * CH, e = min(s + CH, E);
    for (int i = s + t; i < e; i += 256) atomicAdd(&h[dst[i] >> BUK_SH], 1);
    __syncthreads();
    for (int i = t; i < NBUK; i += 256) hist[i * NCH + c] = h[i];
}

__global__ __launch_bounds__(256) void k_scanBkt(int* __restrict__ hist,
                                                 int* __restrict__ bktTot) {
    __shared__ int sh[256];
    int b = blockIdx.x, t = threadIdx.x;
    int v = hist[b * NCH + t];
    sh[t] = v;
    __syncthreads();
    for (int off = 1; off < 256; off <<= 1) {
        int x = (t >= off) ? sh[t - off] : 0;
        __syncthreads();
        sh[t] += x;
        __syncthreads();
    }
    hist[b * NCH + t] = sh[t] - v;
    if (t == 255) bktTot[b] = sh[255];
}

// single-block scan of up to 1024 bucket totals -> bktBase[0..NBUK]
__global__ __launch_bounds__(256) void k_scanTot(const int* __restrict__ bktTot,
                                                 int* __restrict__ bktBase, int NBUK) {
    __shared__ int sh[256];
    int t = threadIdx.x;
    int base = t * 4;
    int v0 = (base + 0 < NBUK) ? bktTot[base + 0] : 0;
    int v1 = (base + 1 < NBUK) ? bktTot[base + 1] : 0;
    int v2 = (base + 2 < NBUK) ? bktTot[base + 2] : 0;
    int v3 = (base + 3 < NBUK) ? bktTot[base + 3] : 0;
    int s = v0 + v1 + v2 + v3;
    sh[t] = s;
    __syncthreads();
    for (int off = 1; off < 256; off <<= 1) {
        int x = (t >= off) ? sh[t - off] : 0;
        __syncthreads();
        sh[t] += x;
        __syncthreads();
    }
    int excl = sh[t] - s;
    if (base + 0 < NBUK) bktBase[base + 0] = excl;
    if (base + 1 < NBUK) bktBase[base + 1] = excl + v0;
    if (base + 2 < NBUK) bktBase[base + 2] = excl + v0 + v1;
    if (base + 3 < NBUK) bktBase[base + 3] = excl + v0 + v1 + v2;
    if (t == 255) bktBase[NBUK] = sh[255];
}

// record = src | dlocal<<20   (src < 2^20, dlocal < 128)
__global__ __launch_bounds__(256) void k_scatter(const int* __restrict__ src,
                                                 const int* __restrict__ dst,
                                                 const int* __restrict__ hist,
                                                 const int* __restrict__ bktBase,
                                                 uint32_t* __restrict__ binned,
                                                 int E, int CH, int NBUK) {
    __shared__ int ctr[1024];
    int t = threadIdx.x, c = blockIdx.x;
    for (int i = t; i < NBUK; i += 256) ctr[i] = bktBase[i] + hist[i * NCH + c];
    __syncthreads();
    int s = c * CH, e = min(s + CH, E);
    for (int i = s + t; i < e; i += 256) {
        int d = dst[i];
        int pos = atomicAdd(&ctr[d >> BUK_SH], 1);
        binned[pos] = (uint32_t)src[i] | ((uint32_t)(d & (BN - 1)) << 20);
    }
}

// ---- Layer 1 GEMM via MFMA (inline W swizzle fp32->fp16) ---------------
__global__ __launch_bounds__(256) void k_gemm1m(
        const float* __restrict__ X,
        const float* __restrict__ W1l, const float* __restrict__ W1r,
        _Float16* __restrict__ xlh, _Float16* __restrict__ xrh, int N) {
    __shared__ _Float16 Ws[16384];
    __shared__ _Float16 Xs[128 * 136];
    int t = threadIdx.x;
    int n0 = blockIdx.x * 128;
    int validRows = N - n0; if (validRows > 128) validRows = 128;
    for (int i = t; i < 4096; i += 256) {
        int k = i >> 5, c4 = (i & 31) << 2;
        float4 v = (c4 < 64) ? *(const float4*)&W1l[k * 64 + c4]
                             : *(const float4*)&W1r[k * 64 + (c4 - 64)];
        int s = k >> 5, q = (k >> 3) & 3, j = k & 7;
        float vv[4] = {v.x, v.y, v.z, v.w};
#pragma unroll
        for (int u = 0; u < 4; ++u) {
            int C = c4 + u, c = C >> 4, n = C & 15;
            Ws[(((c * 4 + s) * 4 + q) * 16 + n) * 8 + j] = (_Float16)vv[u];
        }
    }
    for (int i = t; i < 4096; i += 256) {
        int r = i >> 5, c4 = (i & 31) << 2;
        float4 v = {0.f, 0.f, 0.f, 0.f};
        if (r < validRows) v = *(const float4*)&X[(long)(n0 + r) * 128 + c4];
        half4 hv;
        hv.x = (_Float16)v.x; hv.y = (_Float16)v.y;
        hv.z = (_Float16)v.z; hv.w = (_Float16)v.w;
        *(half4*)&Xs[r * 136 + c4] = hv;
    }
    __syncthreads();
    int w = t >> 6, lane = t & 63;
    int m = lane & 15, q = lane >> 4;
    f32x4 acc[2][8];
#pragma unroll
    for (int a = 0; a < 2; ++a)
#pragma unroll
        for (int c = 0; c < 8; ++c) acc[a][c] = (f32x4){0.f, 0.f, 0.f, 0.f};
#pragma unroll
    for (int s = 0; s < 4; ++s) {
        f16x8 a0 = *(const f16x8*)&Xs[(w * 32 + m) * 136 + s * 32 + q * 8];
        f16x8 a1 = *(const f16x8*)&Xs[(w * 32 + 16 + m) * 136 + s * 32 + q * 8];
#pragma unroll
        for (int c = 0; c < 8; ++c) {
            f16x8 b = *(const f16x8*)&Ws[(((c * 4 + s) * 4 + q) * 16 + m) * 8];
            acc[0][c] = __builtin_amdgcn_mfma_f32_16x16x32_f16(a0, b, acc[0][c], 0, 0, 0);
            acc[1][c] = __builtin_amdgcn_mfma_f32_16x16x32_f16(a1, b, acc[1][c], 0, 0, 0);
        }
    }
#pragma unroll
    for (int sub = 0; sub < 2; ++sub)
#pragma unroll
    for (int c = 0; c < 8; ++c)
#pragma unroll
    for (int r = 0; r < 4; ++r) {
        int gn = n0 + w * 32 + sub * 16 + q * 4 + r;
        if (gn < N) {
            int C = c * 16 + m;
            _Float16 v = (_Float16)acc[sub][c][r];
            if (C < 64) xlh[(long)gn * 64 + C] = v;
            else        xrh[(long)gn * 64 + (C - 64)] = v;
        }
    }
}

// ---- Layer 2 GEMM via MFMA (fp16 H input, inline W swizzle) ------------
__global__ __launch_bounds__(256) void k_gemm2m(
        const _Float16* __restrict__ Hm,
        const float* __restrict__ W2l, const float* __restrict__ W2r,
        _Float16* __restrict__ xlh, _Float16* __restrict__ xrh, int N) {
    __shared__ _Float16 Ws2[2048];
    __shared__ _Float16 Hs[256 * 72];
    int t = threadIdx.x;
    int n0 = blockIdx.x * 256;
    int validRows = N - n0; if (validRows > 256) validRows = 256;
    for (int i = t; i < 512; i += 256) {
        int k = i >> 3, c4 = (i & 7) << 2;
        float4 v = (c4 < 16) ? *(const float4*)&W2l[k * 16 + c4]
                             : *(const float4*)&W2r[k * 16 + (c4 - 16)];
        int s = k >> 5, q = (k >> 3) & 3, j = k & 7;
        float vv[4] = {v.x, v.y, v.z, v.w};
#pragma unroll
        for (int u = 0; u < 4; ++u) {
            int C = c4 + u, c = C >> 4, n = C & 15;
            Ws2[(((c * 2 + s) * 4 + q) * 16 + n) * 8 + j] = (_Float16)vv[u];
        }
    }
    for (int i = t; i < 2048; i += 256) {
        int r = i >> 3, c8 = (i & 7) << 3;
        f16x8 v = {0, 0, 0, 0, 0, 0, 0, 0};
        if (r < validRows) v = *(const f16x8*)&Hm[(long)(n0 + r) * 64 + c8];
        *(f16x8*)&Hs[r * 72 + c8] = v;
    }
    __syncthreads();
    int w = t >> 6, lane = t & 63;
    int m = lane & 15, q = lane >> 4;
    f32x4 acc[4][2];
#pragma unroll
    for (int a = 0; a < 4; ++a)
#pragma unroll
        for (int c = 0; c < 2; ++c) acc[a][c] = (f32x4){0.f, 0.f, 0.f, 0.f};
#pragma unroll
    for (int s = 0; s < 2; ++s) {
        f16x8 a[4];
#pragma unroll
        for (int sub = 0; sub < 4; ++sub)
            a[sub] = *(const f16x8*)&Hs[(w * 64 + sub * 16 + m) * 72 + s * 32 + q * 8];
#pragma unroll
        for (int c = 0; c < 2; ++c) {
            f16x8 b = *(const f16x8*)&Ws2[(((c * 2 + s) * 4 + q) * 16 + m) * 8];
#pragma unroll
            for (int sub = 0; sub < 4; ++sub)
                acc[sub][c] = __builtin_amdgcn_mfma_f32_16x16x32_f16(a[sub], b, acc[sub][c], 0, 0, 0);
        }
    }
#pragma unroll
    for (int sub = 0; sub < 4; ++sub)
#pragma unroll
    for (int c = 0; c < 2; ++c)
#pragma unroll
    for (int r = 0; r < 4; ++r) {
        int gn = n0 + w * 64 + sub * 16 + q * 4 + r;
        if (gn < N) {
            int C = c * 16 + m;
            _Float16 v = (_Float16)acc[sub][c][r];
            if (C < 16) xlh[(long)gn * 16 + C] = v;
            else        xrh[(long)gn * 16 + (C - 16)] = v;
        }
    }
}

// ---- Attention layer 1: bucket-streaming, LDS accumulate ---------------
// o[nd][dim] fp32, row stride 65 (odd -> bank-spread); l separate.
__global__ __launch_bounds__(256) void k_att1L(
        const f16x8* __restrict__ xlh, const f16x8* __restrict__ xrh,
        const float* __restrict__ a1, const float* __restrict__ b1,
        const uint32_t* __restrict__ binned, const int* __restrict__ bktBase,
        _Float16* __restrict__ hout, int N) {
    __shared__ float o[BN * 65];
    __shared__ float lAcc[BN];
    __shared__ _Float16 xrs[BN * 64];
    int b = blockIdx.x, t = threadIdx.x;
    int n0 = b << BUK_SH;
    for (int i = t; i < BN * 65; i += 256) o[i] = 0.f;
    if (t < BN) lAcc[t] = 0.f;
    for (int i = t; i < BN * 8; i += 256) {
        int nd = i >> 3, q8 = i & 7;
        f16x8 v = {0, 0, 0, 0, 0, 0, 0, 0};
        if (n0 + nd < N) v = xrh[(long)(n0 + nd) * 8 + q8];
        *(f16x8*)&xrs[nd * 64 + q8 * 8] = v;
    }
    __syncthreads();
    int lane = t & 63, wv = t >> 6;
    int q = lane & 7, g = lane >> 3;
    float4 af0 = ((const float4*)a1)[q * 2 + 0];
    float4 af1 = ((const float4*)a1)[q * 2 + 1];
    half2v a01 = {(_Float16)af0.x, (_Float16)af0.y};
    half2v a23 = {(_Float16)af0.z, (_Float16)af0.w};
    half2v a45 = {(_Float16)af1.x, (_Float16)af1.y};
    half2v a67 = {(_Float16)af1.z, (_Float16)af1.w};
    // self-loop pass: 128 synthetic edges
    for (int idx = wv * 8 + g; idx < BN; idx += 32) {
        int gn = n0 + idx;
        bool valid = gn < N;
        f16x8 xh = xlh[(long)(valid ? gn : n0) * 8 + q];
        f16x8 xrv = *(const f16x8*)&xrs[idx * 64 + q * 8];
        f16x8 tt = xh + xrv;
        f16x8 u = __builtin_elementwise_max(tt, tt * (_Float16)0.2f);
        half2v ua = {u[0], u[1]}, ub = {u[2], u[3]}, uc = {u[4], u[5]}, ud = {u[6], u[7]};
        float e = __builtin_amdgcn_fdot2(ua, a01,
                   __builtin_amdgcn_fdot2(ub, a23,
                    __builtin_amdgcn_fdot2(uc, a45,
                     __builtin_amdgcn_fdot2(ud, a67, 0.f, false), false), false), false);
#pragma unroll
        for (int off = 1; off < 8; off <<= 1) e += __shfl_xor(e, off, 8);
        float c = valid ? __expf(e) : 0.f;
#pragma unroll
        for (int k = 0; k < 8; ++k)
            atomicAdd(&o[idx * 65 + q * 8 + k], c * (float)xh[k]);
        if (q == 0) atomicAdd(&lAcc[idx], c);
    }
    // main edge stream
    int s = bktBase[b], e_end = bktBase[b + 1];
    for (int i = s + wv * 8; i < e_end; i += 32) {
        int ie = i + g;
        bool valid = ie < e_end;
        uint32_t p = binned[valid ? ie : (e_end - 1)];
        int src = (int)(p & 0xFFFFFu);
        int nd = (int)(p >> 20) & (BN - 1);
        f16x8 xh = xlh[(long)src * 8 + q];
        f16x8 xrv = *(const f16x8*)&xrs[nd * 64 + q * 8];
        f16x8 tt = xh + xrv;
        f16x8 u = __builtin_elementwise_max(tt, tt * (_Float16)0.2f);
        half2v ua = {u[0], u[1]}, ub = {u[2], u[3]}, uc = {u[4], u[5]}, ud = {u[6], u[7]};
        float e = __builtin_amdgcn_fdot2(ua, a01,
                   __builtin_amdgcn_fdot2(ub, a23,
                    __builtin_amdgcn_fdot2(uc, a45,
                     __builtin_amdgcn_fdot2(ud, a67, 0.f, false), false), false), false);
#pragma unroll
        for (int off = 1; off < 8; off <<= 1) e += __shfl_xor(e, off, 8);
        float c = valid ? __expf(e) : 0.f;
#pragma unroll
        for (int k = 0; k < 8; ++k)
            atomicAdd(&o[nd * 65 + q * 8 + k], c * (float)xh[k]);
        if (q == 0) atomicAdd(&lAcc[nd], c);
    }
    __syncthreads();
    // epilogue: 2 threads/node
    int nd = t >> 1, hf = t & 1;
    int gn = n0 + nd;
    if (gn < N) {
        float rl = 1.f / lAcc[nd];
        _Float16 hv[32];
#pragma unroll
        for (int d = 0; d < 32; ++d) {
            int dim = hf * 32 + d;
            float h = o[nd * 65 + dim] * rl + b1[dim];
            h = (h > 0.f) ? h : (__expf(h) - 1.f);
            hv[d] = (_Float16)h;
        }
#pragma unroll
        for (int j = 0; j < 4; ++j)
            hout[(long)gn * 64 + hf * 32 + j * 8 + 0] = hv[j * 8];  // placeholder
        // vector store (overwrite placeholder properly):
#pragma unroll
        for (int j = 0; j < 4; ++j)
            *(f16x8*)&hout[(long)gn * 64 + hf * 32 + j * 8] = *(f16x8*)&hv[j * 8];
    }
}

// ---- Attention layer 2: bucket-streaming + row softmax -----------------
__global__ __launch_bounds__(256) void k_att2L(
        const half4* __restrict__ xlh, const half4* __restrict__ xrh,
        const float* __restrict__ a2, const float* __restrict__ b2v,
        const uint32_t* __restrict__ binned, const int* __restrict__ bktBase,
        float* __restrict__ out, int N) {
    __shared__ float o2[BN * 19];
    __shared__ float l2[BN];
    __shared__ _Float16 xr2s[BN * 16];
    int b = blockIdx.x, t = threadIdx.x;
    int n0 = b << BUK_SH;
    for (int i = t; i < BN * 19; i += 256) o2[i] = 0.f;
    if (t < BN) l2[t] = 0.f;
    for (int i = t; i < BN * 4; i += 256) {
        int nd = i >> 2, q4 = i & 3;
        half4 v = {0, 0, 0, 0};
        if (n0 + nd < N) v = xrh[(long)(n0 + nd) * 4 + q4];
        *(half4*)&xr2s[nd * 16 + q4 * 4] = v;
    }
    __syncthreads();
    int lane = t & 63, wv = t >> 6;
    int q = lane & 3, g = lane >> 2;
    float4 af = ((const float4*)a2)[q];
    half2v alo = {(_Float16)af.x, (_Float16)af.y};
    half2v ahi = {(_Float16)af.z, (_Float16)af.w};
    // self-loops
    for (int idx = wv * 16 + g; idx < BN; idx += 64) {
        int gn = n0 + idx;
        bool valid = gn < N;
        half4 xh = xlh[(long)(valid ? gn : n0) * 4 + q];
        half4 xrv = *(const half4*)&xr2s[idx * 16 + q * 4];
        half4 tt = xh + xrv;
        half4 u = __builtin_elementwise_max(tt, tt * (_Float16)0.2f);
        half2v ulo = {u.x, u.y}, uhi = {u.z, u.w};
        float e = __builtin_amdgcn_fdot2(ulo, alo,
                   __builtin_amdgcn_fdot2(uhi, ahi, 0.f, false), false);
        e += __shfl_xor(e, 1, 4);
        e += __shfl_xor(e, 2, 4);
        float c = valid ? __expf(e) : 0.f;
        atomicAdd(&o2[idx * 19 + q * 4 + 0], c * (float)xh.x);
        atomicAdd(&o2[idx * 19 + q * 4 + 1], c * (float)xh.y);
        atomicAdd(&o2[idx * 19 + q * 4 + 2], c * (float)xh.z);
        atomicAdd(&o2[idx * 19 + q * 4 + 3], c * (float)xh.w);
        if (q == 0) atomicAdd(&l2[idx], c);
    }
    int s = bktBase[b], e_end = bktBase[b + 1];
    for (int i = s + wv * 16; i < e_end; i += 64) {
        int ie = i + g;
        bool valid = ie < e_end;
        uint32_t p = binned[valid ? ie : (e_end - 1)];
        int src = (int)(p & 0xFFFFFu);
        int nd = (int)(p >> 20) & (BN - 1);
        half4 xh = xlh[(long)src * 4 + q];
        half4 xrv = *(const half4*)&xr2s[nd * 16 + q * 4];
        half4 tt = xh + xrv;
        half4 u = __builtin_elementwise_max(tt, tt * (_Float16)0.2f);
        half2v ulo = {u.x, u.y}, uhi = {u.z, u.w};
        float e = __builtin_amdgcn_fdot2(ulo, alo,
                   __builtin_amdgcn_fdot2(uhi, ahi, 0.f, false), false);
        e += __shfl_xor(e, 1, 4);
        e += __shfl_xor(e, 2, 4);
        float c = valid ? __expf(e) : 0.f;
        atomicAdd(&o2[nd * 19 + q * 4 + 0], c * (float)xh.x);
        atomicAdd(&o2[nd * 19 + q * 4 + 1], c * (float)xh.y);
        atomicAdd(&o2[nd * 19 + q * 4 + 2], c * (float)xh.z);
        atomicAdd(&o2[nd * 19 + q * 4 + 3], c * (float)xh.w);
        if (q == 0) atomicAdd(&l2[nd], c);
    }
    __syncthreads();
    // epilogue: 1 thread/node -> bias, softmax over 16, store
    if (t < BN) {
        int gn = n0 + t;
        if (gn < N) {
            float rl = 1.f / l2[t];
            float z[16];
            float mx = -1e30f;
#pragma unroll
            for (int d = 0; d < 16; ++d) {
                z[d] = o2[t * 19 + d] * rl + b2v[d];
                mx = fmaxf(mx, z[d]);
            }
            float ss = 0.f;
#pragma unroll
            for (int d = 0; d < 16; ++d) { z[d] = __expf(z[d] - mx); ss += z[d]; }
            float rs = 1.f / ss;
#pragma unroll
            for (int d = 0; d < 16; d += 4) {
                float4 v = {z[d] * rs, z[d + 1] * rs, z[d + 2] * rs, z[d + 3] * rs};
                *(float4*)&out[(long)gn * 16 + d] = v;
            }
        }
    }
}

// ---- launch ------------------------------------------------------------
extern "C" void kernel_launch(void* const* d_in, const int* in_sizes, int n_in,
                              void* d_out, int out_size, void* d_ws, size_t ws_size,
                              hipStream_t stream) {
    const float* X   = (const float*)d_in[0];
    const int*   ei  = (const int*)d_in[1];
    const float* W1l = (const float*)d_in[3];
    const float* W1r = (const float*)d_in[4];
    const float* a1  = (const float*)d_in[5];
    const float* b1  = (const float*)d_in[6];
    const float* W2l = (const float*)d_in[7];
    const float* W2r = (const float*)d_in[8];
    const float* a2  = (const float*)d_in[9];
    const float* b2  = (const float*)d_in[10];

    int N = in_sizes[0] / F_DIM;
    int E = in_sizes[1] / 2;
    int NBUK = (N + BN - 1) >> BUK_SH;
    int NH = NBUK * NCH;
    int CH = (E + NCH - 1) / NCH;
    const int* srcv = ei;
    const int* dstv = ei + E;

    char* w = (char*)d_ws;
    size_t off = 0;
    auto alloc = [&](size_t bytes) -> char* {
        char* p = w + off;
        off = (off + bytes + 255) & ~(size_t)255;
        return p;
    };
    int* hist    = (int*)alloc((size_t)NH * sizeof(int));
    int* bktTot  = (int*)alloc((size_t)NBUK * sizeof(int));
    int* bktBase = (int*)alloc((size_t)(NBUK + 1) * sizeof(int));
    uint32_t* binned = (uint32_t*)alloc((size_t)E * sizeof(uint32_t));
    _Float16* xl1h = (_Float16*)alloc((size_t)N * H_DIM * 2);
    _Float16* xr1h = (_Float16*)alloc((size_t)N * H_DIM * 2);
    _Float16* h1h  = (_Float16*)alloc((size_t)N * H_DIM * 2);
    _Float16* xl2h = (_Float16*)alloc((size_t)N * K_DIM * 2);
    _Float16* xr2h = (_Float16*)alloc((size_t)N * K_DIM * 2);

    // edge binning (4 launches)
    k_hist<<<NCH, 256, 0, stream>>>(dstv, hist, E, CH, NBUK);
    k_scanBkt<<<NBUK, 256, 0, stream>>>(hist, bktTot);
    k_scanTot<<<1, 256, 0, stream>>>(bktTot, bktBase, NBUK);
    k_scatter<<<NCH, 256, 0, stream>>>(srcv, dstv, hist, bktBase, binned, E, CH, NBUK);

    // layers (4 launches)
    int g1Blocks = (N + 127) / 128;
    k_gemm1m<<<g1Blocks, 256, 0, stream>>>(X, W1l, W1r, xl1h, xr1h, N);
    k_att1L<<<NBUK, 256, 0, stream>>>((const f16x8*)xl1h, (const f16x8*)xr1h,
                                      a1, b1, binned, bktBase, h1h, N);
    int g2Blocks = (N + 255) / 256;
    k_gemm2m<<<g2Blocks, 256, 0, stream>>>(h1h, W2l, W2r, xl2h, xr2h, N);
    k_att2L<<<NBUK, 256, 0, stream>>>((const half4*)xl2h, (const half4*)xr2h,
                                      a2, b2, binned, bktBase, (float*)d_out, N);
}